// Round 8
// baseline (344.482 us; speedup 1.0000x reference)
//
#include <hip/hip_runtime.h>
#include <math.h>

// fp32 in / fp32 out. Six kernel symbols (conv5 / p0 / attn / ffn1 / conv6 / ffn2).
// B=2,T=2048,D=1024,NH=16,NKV=4,HD=64,WIN=128,M=4096.
//
// r8 design: ALL GEMMs are LDS-free (attention-v2 trick generalized).
// Operands live in bf16 "fragment-major" layout FM[row>>4][col>>5][row&15][col&31]
// so an MFMA A/B fragment load (A[m=l16][k=quad*8+j], HW-verified m89/m91) is a
// single lane-contiguous 1KB coalesced global_load_dwordx4:
//   addr = ((rtile*K32 + ktile)*512) + l16*32 + quad*8     (elems, K32=K/32)
// Operands are L1/L2-resident (each matrix 2-8 MiB; H streams via L3), so LDS
// staging + per-K-step barriers (the ~565-600 TF limiter, r7 counters: MfmaUtil
// 22.7 / VALU 10 / HBM 14 = nothing saturated) are pure overhead. No barriers
// anywhere -> compiler software-pipelines the K-loop freely.
//
// ws layout (float slots):
//   q_bf   @ 0           : Q bf16 [4096][1024] rows, RoPE'd, pre-scaled (attn layout)
//   k_bf   @ 2,097,152   : K bf16 [4096][256], RoPE'd
//   vt_bf  @ 2,621,440   : V^T bf16 [2][4][64][2048]
//   xt     @ 6,291,456   : x bf16 FM (K32=32)          (dead after p0)
//   wqkvt  @ 8,388,608   : Wqkv bf16 FM [96 nt][32]    (dead after p0)
//   o_t    @ 8,388,608   : attn out bf16 FM (K32=32)   (over wqkvt; dead after ffn1)
//   w1t    @ 10,485,760  : W1 bf16 FM (K32=32)         (dead after ffn1)
//   h_t    @ 0           : FFN1 out bf16 FM (K32=128)  (over dead q/k/vt/xt)
//   w2t    @ 8,388,608   : W2 bf16 FM (K32=128)        (over dead o_t, conv6)
//
// Sequence: conv5 (x,Wqkv,W1 -> FM bf16; zero out) | p0 QKV+RoPE -> q/k/vt |
//   attn -> o_t | ffn1 (silu -> h_t) | conv6 (W2 -> w2t) | ffn2 (splitK x2,
//   atomicAdd out).  T1 XCD swizzle on all GEMM/attn grids.

typedef __bf16 bf16x8 __attribute__((ext_vector_type(8)));
typedef __bf16 bf16x4 __attribute__((ext_vector_type(4)));
typedef float  f32x4  __attribute__((ext_vector_type(4)));

__device__ __forceinline__ unsigned pk2(float a, float b) {
    union { __bf16 h[2]; unsigned u; } t;
    t.h[0] = (__bf16)a; t.h[1] = (__bf16)b;
    return t.u;
}

__device__ __forceinline__ int xcd_swz(int bid, int n) {
    return (bid & 7) * (n >> 3) + (bid >> 3);
}

// convert one 16B fragment-major chunk: src f32 row-major, dst bf16 FM
__device__ __forceinline__ void fm_chunk(const float* src, __bf16* dst8) {
    const f32x4 a = *(const f32x4*)src;
    const f32x4 b = *(const f32x4*)(src + 4);
    bf16x8 o;
    o[0] = (__bf16)a[0]; o[1] = (__bf16)a[1];
    o[2] = (__bf16)a[2]; o[3] = (__bf16)a[3];
    o[4] = (__bf16)b[0]; o[5] = (__bf16)b[1];
    o[6] = (__bf16)b[2]; o[7] = (__bf16)b[3];
    *(bf16x8*)dst8 = o;
}

// ---------------------------------------------------------------- conv5 ----
// x, Wq|Wk|Wv, W1 -> fragment-major bf16 (all K=1024, K32=32); zero `out`.
// chunk c (16B): kq=c&3, nin=(c>>2)&15, kt=(c>>6)&31, nt=c>>11;
//   row=nt*16+nin, col=kt*32+kq*8; dst elem = c*8.
__global__ __launch_bounds__(256) void MultiAttention_60722247631706_conv5(
    const float* x, const float* Wq, const float* Wk, const float* Wv,
    const float* W1, float* out, float* ws)
{
    __bf16* xt    = (__bf16*)(ws + 6291456);
    __bf16* wqkvt = (__bf16*)(ws + 8388608);
    __bf16* w1t   = (__bf16*)(ws + 10485760);
    const int tid = threadIdx.x;

    const int XC = 524288, WQC = 196608, W1C = 524288;   // chunks
    const int total = XC + WQC + W1C;
    for (int i = blockIdx.x * 256 + tid; i < total;
         i += gridDim.x * 256) {
        int c; const float* srcm; __bf16* dstm; int ldsrc = 1024;
        int rowoff = 0;
        if (i < XC)            { c = i;            srcm = x;  dstm = xt; }
        else if (i < XC + WQC) { c = i - XC;       srcm = 0;  dstm = wqkvt; }
        else                   { c = i - XC - WQC; srcm = W1; dstm = w1t; }
        const int kq  = c & 3;
        const int nin = (c >> 2) & 15;
        const int kt  = (c >> 6) & 31;
        const int nt  = c >> 11;
        const int row = nt * 16 + nin;
        const int col = kt * 32 + kq * 8;
        const float* src;
        if (srcm) {
            src = srcm + (size_t)row * ldsrc + col;
        } else {
            // Wqkv: rows 0..1023 Wq, 1024..1279 Wk, 1280..1535 Wv
            if (row < 1024)      src = Wq + (size_t)row * 1024 + col;
            else if (row < 1280) src = Wk + (size_t)(row - 1024) * 1024 + col;
            else                 src = Wv + (size_t)(row - 1280) * 1024 + col;
        }
        fm_chunk(src, dstm + (size_t)c * 8);
        (void)rowoff;
    }
    // zero out (for ffn2 atomic split-K)
    const f32x4 z = {0.f, 0.f, 0.f, 0.f};
    for (int i4 = blockIdx.x * 256 + tid; i4 < 1048576;
         i4 += gridDim.x * 256) {
        *(f32x4*)(out + (size_t)i4 * 4) = z;
    }
}

// ---------------------------------------------------------------- conv6 ----
// W2 [1024][4096] -> fragment-major bf16 (K32=128).
__global__ __launch_bounds__(256) void MultiAttention_60722247631706_conv6(
    const float* W2, float* ws)
{
    __bf16* w2t = (__bf16*)(ws + 8388608);
    const int tid = threadIdx.x;
    for (int c = blockIdx.x * 256 + tid; c < 524288;
         c += gridDim.x * 256) {
        const int kq  = c & 3;
        const int nin = (c >> 2) & 15;
        const int kt  = (c >> 6) & 127;
        const int nt  = c >> 13;
        const float* src = W2 + (size_t)(nt * 16 + nin) * 4096 + kt * 32 + kq * 8;
        fm_chunk(src, w2t + (size_t)c * 8);
    }
}

// ---------------------------------------------------------------- attn ----
// v2 (unchanged logic): no LDS, no barriers. Grid 1024 = (b, kvh, qt of 16),
// 4 waves = 4 GQA heads. Epilogue now stores o in FRAGMENT-MAJOR (for ffn1).
__global__ __launch_bounds__(256, 4) void MultiAttention_60722247631706_attn(
    float* ws)
{
    const __bf16* qbf  = (const __bf16*)ws;
    const __bf16* kbf  = (const __bf16*)(ws + 2097152);
    const __bf16* vtbf = (const __bf16*)(ws + 2621440);
    __bf16*       obf  = (__bf16*)(ws + 8388608);   // fragment-major

    const int sb  = xcd_swz(blockIdx.x, 1024);
    const int qt  = sb & 127;
    const int kvh = (sb >> 7) & 3;
    const int b   = sb >> 9;
    const int q0  = qt * 16;
    const int wb  = q0 - 128;

    const int tid  = threadIdx.x;
    const int w    = tid >> 6;
    const int lane = tid & 63;
    const int l16  = lane & 15;
    const int quad = lane >> 4;
    const int h    = kvh * 4 + w;

    const __bf16* Kb = kbf + (size_t)b * 2048 * 256 + kvh * 64;
    const __bf16* Vb = vtbf + (size_t)(b * 4 + kvh) * 64 * 2048;

    bf16x8 qf[2];
#pragma unroll
    for (int kk = 0; kk < 2; ++kk)
        qf[kk] = *(const bf16x8*)(qbf + (size_t)(b * 2048 + q0 + l16) * 1024
                                  + h * 64 + kk * 32 + quad * 8);

    f32x4 oacc[4];
#pragma unroll
    for (int dn = 0; dn < 4; ++dn) {
        f32x4 z = {0.f, 0.f, 0.f, 0.f};
        oacc[dn] = z;
    }
    float m_run = -1e30f, l_run = 0.f;
    const int kclip = -wb;

    for (int kb = 0; kb < 3; ++kb) {
        f32x4 s[4];
#pragma unroll
        for (int km = 0; km < 4; ++km) {
            f32x4 z = {0.f, 0.f, 0.f, 0.f};
            s[km] = z;
        }
#pragma unroll
        for (int kk = 0; kk < 2; ++kk) {
            bf16x8 kf[4];
#pragma unroll
            for (int km = 0; km < 4; ++km) {
                int row = wb + kb * 64 + km * 16 + l16;
                row = (row >= 0 && row < 2048) ? row : 0;   // masked anyway
                kf[km] = *(const bf16x8*)(Kb + (size_t)row * 256
                                          + kk * 32 + quad * 8);
            }
#pragma unroll
            for (int km = 0; km < 4; ++km)
                s[km] = __builtin_amdgcn_mfma_f32_16x16x32_bf16(
                    kf[km], qf[kk], s[km], 0, 0, 0);
        }

        float mx = -1e30f;
#pragma unroll
        for (int km = 0; km < 4; ++km)
#pragma unroll
            for (int r = 0; r < 4; ++r) {
                const int kl  = kb * 64 + km * 16 + quad * 4 + r;
                const int dlt = kl - l16;
                const bool ok = (dlt >= 1) && (dlt <= 128) && (kl >= kclip);
                const float sv = ok ? s[km][r] : -1e30f;
                s[km][r] = sv;
                mx = fmaxf(mx, sv);
            }
        mx = fmaxf(mx, __shfl_xor(mx, 16));
        mx = fmaxf(mx, __shfl_xor(mx, 32));
        const float mnew = fmaxf(fmaxf(m_run, mx), -1e20f);
        const float corr = expf(m_run - mnew);
        m_run = mnew;
        float rowsum = 0.f;
        unsigned cu[4][2];
#pragma unroll
        for (int km = 0; km < 4; ++km) {
#pragma unroll
            for (int r = 0; r < 4; ++r) {
                const float p = expf(s[km][r] - mnew);
                s[km][r] = p;
                rowsum += p;
            }
            cu[km][0] = pk2(s[km][0], s[km][1]);
            cu[km][1] = pk2(s[km][2], s[km][3]);
        }
        rowsum += __shfl_xor(rowsum, 16);
        rowsum += __shfl_xor(rowsum, 32);
        l_run = l_run * corr + rowsum;

#pragma unroll
        for (int r = 0; r < 4; ++r) {
            const float f = __shfl(corr, (lane & 48) | (quad * 4 + r));
            oacc[0][r] *= f; oacc[1][r] *= f;
            oacc[2][r] *= f; oacc[3][r] *= f;
        }

#pragma unroll
        for (int kk = 0; kk < 2; ++kk) {
            bf16x8 vf[4];
#pragma unroll
            for (int dn = 0; dn < 4; ++dn) {
                int t = wb + kb * 64 + kk * 32 + quad * 8;
                t = (t >= 0 && t <= 2040) ? t : 0;
                vf[dn] = *(const bf16x8*)(Vb + (size_t)(dn * 16 + l16) * 2048 + t);
            }
            const int srcA = ((quad & 1) * 32) + l16;
            const int hi   = quad >> 1;
            const unsigned a0 = (unsigned)__shfl((int)cu[2*kk  ][0], srcA);
            const unsigned a1 = (unsigned)__shfl((int)cu[2*kk  ][1], srcA);
            const unsigned b0 = (unsigned)__shfl((int)cu[2*kk+1][0], srcA);
            const unsigned b1 = (unsigned)__shfl((int)cu[2*kk+1][1], srcA);
            const unsigned c0 = (unsigned)__shfl((int)cu[2*kk  ][0], srcA + 16);
            const unsigned c1 = (unsigned)__shfl((int)cu[2*kk  ][1], srcA + 16);
            const unsigned d0 = (unsigned)__shfl((int)cu[2*kk+1][0], srcA + 16);
            const unsigned d1 = (unsigned)__shfl((int)cu[2*kk+1][1], srcA + 16);
            union { unsigned u[4]; bf16x8 v; } af;
            af.u[0] = hi ? b0 : a0;
            af.u[1] = hi ? b1 : a1;
            af.u[2] = hi ? d0 : c0;
            af.u[3] = hi ? d1 : c1;
#pragma unroll
            for (int dn = 0; dn < 4; ++dn)
                oacc[dn] = __builtin_amdgcn_mfma_f32_16x16x32_bf16(
                    af.v, vf[dn], oacc[dn], 0, 0, 0);
        }
    }

    // store o in fragment-major: row m = b*2048+q0+quad*4+r (mtile = b*128+qt),
    // col k = h*64+dn*16+l16 -> kt = h*2+(dn>>1), k&31 = (dn&1)*16+l16.
    const float rl = 1.f / l_run;
    __bf16* ob = obf + ((size_t)(b * 128 + qt) * 32 + h * 2) * 512 + l16;
#pragma unroll
    for (int r = 0; r < 4; ++r) {
        const float f = __shfl(rl, (lane & 48) | (quad * 4 + r));
        __bf16* obr = ob + (quad * 4 + r) * 32;
#pragma unroll
        for (int dn = 0; dn < 4; ++dn)
            obr[(dn >> 1) * 512 + (dn & 1) * 16] = (__bf16)(oacc[dn][r] * f);
    }
}

// ------------------------------------------------------------------ p0 ----
// Y=QKV GEMM + fused RoPE -> q/k/vt (attn layouts). LDS-free fragment-direct.
// 64x128 tile, grid 768 (3/CU), 4 waves 2x2, acc[2][4].
__global__ __launch_bounds__(256, 4) void MultiAttention_60722247631706_p0(
    float* ws)
{
    __bf16* qbf    = (__bf16*)ws;
    __bf16* kbf    = (__bf16*)(ws + 2097152);
    __bf16* vtbf   = (__bf16*)(ws + 2621440);
    const __bf16* xt    = (const __bf16*)(ws + 6291456);
    const __bf16* wqkvt = (const __bf16*)(ws + 8388608);

    const int tid  = threadIdx.x;
    const int bid  = xcd_swz(blockIdx.x, 768);
    const int tm   = bid / 12;        // 0..63
    const int tn   = bid % 12;        // 0..11
    const int w    = tid >> 6;
    const int lane = tid & 63;
    const int wr   = w >> 1;
    const int wc   = w & 1;
    const int l16  = lane & 15;
    const int quad = lane >> 4;
    const int lo   = l16 * 32 + quad * 8;   // lane offset within a frag tile

    f32x4 zero = {0.f, 0.f, 0.f, 0.f};
    f32x4 acc[2][4];
#pragma unroll
    for (int mi = 0; mi < 2; ++mi)
#pragma unroll
        for (int ni = 0; ni < 4; ++ni) acc[mi][ni] = zero;

    for (int k0 = 0; k0 < 1024; k0 += 64) {
#pragma unroll
        for (int kk = 0; kk < 2; ++kk) {
            const int kt = (k0 >> 5) + kk;
            bf16x8 af[2], bfr[4];
#pragma unroll
            for (int mi = 0; mi < 2; ++mi)
                af[mi] = *(const bf16x8*)(xt +
                    ((size_t)(tm * 4 + wr * 2 + mi) * 32 + kt) * 512 + lo);
#pragma unroll
            for (int ni = 0; ni < 4; ++ni)
                bfr[ni] = *(const bf16x8*)(wqkvt +
                    ((size_t)(tn * 8 + wc * 4 + ni) * 32 + kt) * 512 + lo);
#pragma unroll
            for (int mi = 0; mi < 2; ++mi)
#pragma unroll
                for (int ni = 0; ni < 4; ++ni)
                    acc[mi][ni] = __builtin_amdgcn_mfma_f32_16x16x32_bf16(
                        af[mi], bfr[ni], acc[mi][ni], 0, 0, 0);
        }
    }

    const int mbase = tm * 64 + wr * 32;
    const int nbase = tn * 128 + wc * 64;   // multiple of 64 -> head-aligned

    if (nbase < 1280) {
        const bool isQ = nbase < 1024;
        const float inv1 = powf(10000.f, -(float)l16 / 32.f);
        const float inv2 = powf(10000.f, -(float)(16 + l16) / 32.f);
#pragma unroll
        for (int mi = 0; mi < 2; ++mi) {
#pragma unroll
            for (int r = 0; r < 4; ++r) {
                const int m = mbase + mi * 16 + quad * 4 + r;
                const int t = m & 2047;
                float v0 = acc[mi][0][r], v1 = acc[mi][1][r];
                float v2 = acc[mi][2][r], v3 = acc[mi][3][r];
                const float a1 = (float)t * inv1, a2 = (float)t * inv2;
                const float c1 = cosf(a1), s1 = sinf(a1);
                const float c2 = cosf(a2), s2 = sinf(a2);
                float n0 = v0 * c1 - v2 * s1;
                float n2 = v0 * s1 + v2 * c1;
                float n1 = v1 * c2 - v3 * s2;
                float n3 = v1 * s2 + v3 * c2;
                if (isQ) { n0 *= 0.125f; n1 *= 0.125f; n2 *= 0.125f; n3 *= 0.125f; }
                __bf16* dst = isQ
                    ? qbf + (size_t)m * 1024 + nbase + l16
                    : kbf + (size_t)m * 256 + (nbase - 1024) + l16;
                dst[0]  = (__bf16)n0; dst[16] = (__bf16)n1;
                dst[32] = (__bf16)n2; dst[48] = (__bf16)n3;
            }
        }
    } else {
        const int kvh = (nbase - 1280) >> 6;
        const int bb  = mbase >> 11;
        const int tb  = mbase & 2047;
#pragma unroll
        for (int mi = 0; mi < 2; ++mi) {
#pragma unroll
            for (int ni = 0; ni < 4; ++ni) {
                const int d = ni * 16 + l16;
                bf16x4 pv;
                pv[0] = (__bf16)acc[mi][ni][0]; pv[1] = (__bf16)acc[mi][ni][1];
                pv[2] = (__bf16)acc[mi][ni][2]; pv[3] = (__bf16)acc[mi][ni][3];
                *(bf16x4*)(vtbf + ((size_t)(bb * 4 + kvh) * 64 + d) * 2048
                           + tb + mi * 16 + quad * 4) = pv;
            }
        }
    }
}

// ---------------------------------------------------------------- ffn1 ----
// H = silu(o@W1^T), all fragment-direct (o_t, w1t FM K32=32), no LDS/barriers.
// 128x128 tile, grid 1024 (4/CU), acc[4][4]. Output h_t FM (K32=128).
__global__ __launch_bounds__(256, 4) void MultiAttention_60722247631706_ffn1(
    float* ws)
{
    const __bf16* ot  = (const __bf16*)(ws + 8388608);
    const __bf16* w1t = (const __bf16*)(ws + 10485760);
    __bf16*       ht  = (__bf16*)ws;

    const int tid  = threadIdx.x;
    const int bid  = xcd_swz(blockIdx.x, 1024);
    const int tm   = bid >> 5;
    const int tn   = bid & 31;
    const int w    = tid >> 6;
    const int lane = tid & 63;
    const int wr   = w >> 1;
    const int wc   = w & 1;
    const int l16  = lane & 15;
    const int quad = lane >> 4;
    const int lo   = l16 * 32 + quad * 8;

    f32x4 zero = {0.f, 0.f, 0.f, 0.f};
    f32x4 acc[4][4];
#pragma unroll
    for (int mi = 0; mi < 4; ++mi)
#pragma unroll
        for (int ni = 0; ni < 4; ++ni) acc[mi][ni] = zero;

    for (int k0 = 0; k0 < 1024; k0 += 64) {
#pragma unroll
        for (int kk = 0; kk < 2; ++kk) {
            const int kt = (k0 >> 5) + kk;
            bf16x8 af[4], bfr[4];
#pragma unroll
            for (int mi = 0; mi < 4; ++mi)
                af[mi] = *(const bf16x8*)(ot +
                    ((size_t)(tm * 8 + wr * 4 + mi) * 32 + kt) * 512 + lo);
#pragma unroll
            for (int ni = 0; ni < 4; ++ni)
                bfr[ni] = *(const bf16x8*)(w1t +
                    ((size_t)(tn * 8 + wc * 4 + ni) * 32 + kt) * 512 + lo);
#pragma unroll
            for (int mi = 0; mi < 4; ++mi)
#pragma unroll
                for (int ni = 0; ni < 4; ++ni)
                    acc[mi][ni] = __builtin_amdgcn_mfma_f32_16x16x32_bf16(
                        af[mi], bfr[ni], acc[mi][ni], 0, 0, 0);
        }
    }

    // epilogue: silu -> h_t fragment-major (row m, col n; K32=128)
    //   addr = ((m>>4)*128 + (n>>5))*512 + (m&15)*32 + (n&31)
#pragma unroll
    for (int mi = 0; mi < 4; ++mi) {
        const int mtile = tm * 8 + wr * 4 + mi;
        __bf16* hb = ht + ((size_t)mtile * 128 + (tn * 4 + wc * 2)) * 512 + l16;
#pragma unroll
        for (int r = 0; r < 4; ++r) {
            __bf16* hr = hb + (quad * 4 + r) * 32;
#pragma unroll
            for (int ni = 0; ni < 4; ++ni) {
                const float v = acc[mi][ni][r];
                hr[(ni >> 1) * 512 + (ni & 1) * 16] =
                    (__bf16)(v / (1.f + expf(-v)));   // silu
            }
        }
    }
}

// ---------------------------------------------------------------- ffn2 ----
// out += H_ks @ W2_ks^T, fragment-direct (h_t, w2t FM K32=128), no LDS.
// 128x128 tile, split-K x2, grid 512, atomicAdd (out zeroed in conv5).
__global__ __launch_bounds__(256, 4) void MultiAttention_60722247631706_ffn2(
    float* out, float* ws)
{
    const __bf16* ht  = (const __bf16*)ws;
    const __bf16* w2t = (const __bf16*)(ws + 8388608);

    int bid = xcd_swz(blockIdx.x, 512);
    const int ks = bid >> 8;  bid &= 255;
    const int tm = bid >> 3;          // 0..31
    const int tn = bid & 7;           // 0..7
    const int ktb = ks * 64;          // kt base (K-slice of 2048 = 64 ktiles)

    const int tid  = threadIdx.x;
    const int w    = tid >> 6;
    const int lane = tid & 63;
    const int wr   = w >> 1;
    const int wc   = w & 1;
    const int l16  = lane & 15;
    const int quad = lane >> 4;
    const int lo   = l16 * 32 + quad * 8;

    f32x4 zero = {0.f, 0.f, 0.f, 0.f};
    f32x4 acc[4][4];
#pragma unroll
    for (int mi = 0; mi < 4; ++mi)
#pragma unroll
        for (int ni = 0; ni < 4; ++ni) acc[mi][ni] = zero;

    for (int k0 = 0; k0 < 2048; k0 += 64) {
#pragma unroll
        for (int kk = 0; kk < 2; ++kk) {
            const int kt = ktb + (k0 >> 5) + kk;
            bf16x8 af[4], bfr[4];
#pragma unroll
            for (int mi = 0; mi < 4; ++mi)
                af[mi] = *(const bf16x8*)(ht +
                    ((size_t)(tm * 8 + wr * 4 + mi) * 128 + kt) * 512 + lo);
#pragma unroll
            for (int ni = 0; ni < 4; ++ni)
                bfr[ni] = *(const bf16x8*)(w2t +
                    ((size_t)(tn * 8 + wc * 4 + ni) * 128 + kt) * 512 + lo);
#pragma unroll
            for (int mi = 0; mi < 4; ++mi)
#pragma unroll
                for (int ni = 0; ni < 4; ++ni)
                    acc[mi][ni] = __builtin_amdgcn_mfma_f32_16x16x32_bf16(
                        af[mi], bfr[ni], acc[mi][ni], 0, 0, 0);
        }
    }

#pragma unroll
    for (int mi = 0; mi < 4; ++mi) {
#pragma unroll
        for (int r = 0; r < 4; ++r) {
            const int m = tm * 128 + wr * 64 + mi * 16 + quad * 4 + r;
            float* op = out + (size_t)m * 1024 + tn * 128 + wc * 64 + l16;
#pragma unroll
            for (int ni = 0; ni < 4; ++ni)
                atomicAdd(op + ni * 16, acc[mi][ni][r]);
        }
    }
}

extern "C" void kernel_launch(void* const* d_in, const int* in_sizes, int n_in,
                              void* d_out, int out_size, void* d_ws, size_t ws_size,
                              hipStream_t stream)
{
    const float* x  = (const float*)d_in[0];
    const float* Wq = (const float*)d_in[1];
    const float* Wk = (const float*)d_in[2];
    const float* Wv = (const float*)d_in[3];
    const float* W1 = (const float*)d_in[4];
    const float* W2 = (const float*)d_in[5];
    float* out = (float*)d_out;
    float* ws  = (float*)d_ws;

    // conv5: x/Wqkv/W1 -> fragment-major bf16 + zero out
    MultiAttention_60722247631706_conv5<<<2048, 256, 0, stream>>>(
        x, Wq, Wk, Wv, W1, out, ws);
    // p0: QKV GEMM + fused RoPE -> q_bf / k_bf / vt_bf (LDS-free)
    MultiAttention_60722247631706_p0<<<768, 256, 0, stream>>>(ws);
    // attention v2 -> o_t (fragment-major)
    MultiAttention_60722247631706_attn<<<1024, 256, 0, stream>>>(ws);
    // ffn1 -> h_t (fragment-major), LDS-free
    MultiAttention_60722247631706_ffn1<<<1024, 256, 0, stream>>>(ws);
    // conv6: W2 -> w2t (over dead o_t)
    MultiAttention_60722247631706_conv6<<<1024, 256, 0, stream>>>(W2, ws);
    // ffn2: split-K x2, LDS-free, atomicAdd into out
    MultiAttention_60722247631706_ffn2<<<512, 256, 0, stream>>>(out, ws);
}

// Round 9
// 282.865 us; speedup vs baseline: 1.2178x; 1.2178x over previous
//
#include <hip/hip_runtime.h>
#include <math.h>

// fp32 in / fp32 out. Six kernel symbols (conv5 / p0 / attn / ffn1 / conv6 / ffn2).
// B=2,T=2048,D=1024,NH=16,NKV=4,HD=64,WIN=128,M=4096.
//
// r9 design: r7 baseline (247us, verified) + HYBRID ffn GEMMs:
//   A-operand: LDS-staged via global_load_lds + barrier (the latency-hiding
//     skeleton r8 proved is essential), XOR-swizzled reads.
//   B-operand: fragment-major (FM) bf16 global loads — one 1KB lane-contiguous
//     load per fragment (r8-verified addressing). Halves LDS staging writes
//     AND ds_reads (r7 counters: LDS pipe ~2300cyc vs MFMA ~1280cyc per
//     K-step-round = LDS-bound at MfmaUtil 23%).
// FM layout: FM[row>>4][col>>5][row&15][col&31]; frag addr =
//   ((nt*K32 + kt)*512) + l16*32 + quad*8.
//
// ws layout (float slots):
//   q_bf   @ 0           : Q bf16 [4096][1024], RoPE'd, pre-scaled 0.125
//   k_bf   @ 2,097,152   : K bf16 [4096][256], RoPE'd
//   vt_bf  @ 2,621,440   : V^T bf16 [2][4][64][2048]
//   x_bf   @ 6,291,456   : x bf16 [4096][1024] row-major   (dead after p0)
//   wqkv_bf@ 8,388,608   : [1536][1024] bf16 row-major     (dead after p0)
//   o_bf   @ 8,388,608   : attn out bf16 [4096][1024] rows (over wqkv; dead after ffn1)
//   w1t    @ 10,485,760  : W1 bf16 FM K32=32               (dead after ffn1)
//   h_bf   @ 0           : FFN1 out bf16 [4096][4096] rows (over dead q/k/vt/x)
//   w2t    @ 8,388,608   : W2 bf16 FM K32=128              (over dead o_bf, conv6)
//
// Sequence: conv5 (x,wqkv row bf16; W1->FM; zero out) | p0 QKV+RoPE->q/k/vt |
//   attn->o_bf | ffn1 (silu->h_bf) | conv6 (W2->FM) | ffn2 (splitKx2, atomic).
// T1 XCD swizzle everywhere; LDS XOR swizzle on staged A tiles (r2->r3 proven).
// MFMA layouts (HW-verified m89/m91): A[m=lane&15][k=(lane>>4)*8+j],
//   B[n=lane&15][k=same], D: col=lane&15, row=(lane>>4)*4+reg.

typedef __bf16 bf16x8 __attribute__((ext_vector_type(8)));
typedef __bf16 bf16x4 __attribute__((ext_vector_type(4)));
typedef float  f32x4  __attribute__((ext_vector_type(4)));

extern __shared__ __align__(16) char smem[];

#define GLOAD_LDS16(g, l) __builtin_amdgcn_global_load_lds(               \
    (const __attribute__((address_space(1))) void*)(g),                   \
    (__attribute__((address_space(3))) void*)(l), 16, 0, 0)

__device__ __forceinline__ unsigned pk2(float a, float b) {
    union { __bf16 h[2]; unsigned u; } t;
    t.h[0] = (__bf16)a; t.h[1] = (__bf16)b;
    return t.u;
}

__device__ __forceinline__ int xcd_swz(int bid, int n) {
    return (bid & 7) * (n >> 3) + (bid >> 3);
}

__device__ __forceinline__ void fm_chunk(const float* src, __bf16* dst8) {
    const f32x4 a = *(const f32x4*)src;
    const f32x4 b = *(const f32x4*)(src + 4);
    bf16x8 o;
    o[0] = (__bf16)a[0]; o[1] = (__bf16)a[1];
    o[2] = (__bf16)a[2]; o[3] = (__bf16)a[3];
    o[4] = (__bf16)b[0]; o[5] = (__bf16)b[1];
    o[6] = (__bf16)b[2]; o[7] = (__bf16)b[3];
    *(bf16x8*)dst8 = o;
}

// ---------------------------------------------------------------- conv5 ----
// x, Wq|Wk|Wv -> row-major bf16; W1 -> FM bf16 (K32=32); zero `out`.
__global__ __launch_bounds__(256) void MultiAttention_60722247631706_conv5(
    const float* x, const float* Wq, const float* Wk, const float* Wv,
    const float* W1, float* out, float* ws)
{
    __bf16* xbf    = (__bf16*)(ws + 6291456);
    __bf16* wqkvbf = (__bf16*)(ws + 8388608);
    __bf16* w1t    = (__bf16*)(ws + 10485760);
    const int tid = threadIdx.x;

    // part 1: x + Wqkv row-major (elems 0..5,767,168)
    const long long total4 = 5767168 / 4;
    for (long long i4 = (long long)blockIdx.x * 256 + tid; i4 < total4;
         i4 += (long long)gridDim.x * 256) {
        const long long i = i4 * 4;
        const float* src; __bf16* dst;
        if (i < 4194304)      { src = x  + i;             dst = xbf    + i; }
        else if (i < 5242880) { src = Wq + (i - 4194304); dst = wqkvbf + (i - 4194304); }
        else if (i < 5505024) { src = Wk + (i - 5242880); dst = wqkvbf + (i - 4194304); }
        else                  { src = Wv + (i - 5505024); dst = wqkvbf + (i - 4194304); }
        const f32x4 v = *(const f32x4*)src;
        bf16x4 o;
        o[0] = (__bf16)v[0]; o[1] = (__bf16)v[1];
        o[2] = (__bf16)v[2]; o[3] = (__bf16)v[3];
        *(bf16x4*)dst = o;
    }
    // part 2: W1 -> FM chunks (K=1024, K32=32)
    for (int c = blockIdx.x * 256 + tid; c < 524288; c += gridDim.x * 256) {
        const int kq  = c & 3;
        const int nin = (c >> 2) & 15;
        const int kt  = (c >> 6) & 31;
        const int nt  = c >> 11;
        const float* src = W1 + (size_t)(nt * 16 + nin) * 1024 + kt * 32 + kq * 8;
        fm_chunk(src, w1t + (size_t)c * 8);
    }
    // part 3: zero out (for ffn2 atomic split-K)
    const f32x4 z = {0.f, 0.f, 0.f, 0.f};
    for (int i4 = blockIdx.x * 256 + tid; i4 < 1048576; i4 += gridDim.x * 256)
        *(f32x4*)(out + (size_t)i4 * 4) = z;
}

// ---------------------------------------------------------------- conv6 ----
// W2 [1024][4096] -> FM bf16 (K32=128).
__global__ __launch_bounds__(256) void MultiAttention_60722247631706_conv6(
    const float* W2, float* ws)
{
    __bf16* w2t = (__bf16*)(ws + 8388608);
    const int tid = threadIdx.x;
    for (int c = blockIdx.x * 256 + tid; c < 524288; c += gridDim.x * 256) {
        const int kq  = c & 3;
        const int nin = (c >> 2) & 15;
        const int kt  = (c >> 6) & 127;
        const int nt  = c >> 13;
        const float* src = W2 + (size_t)(nt * 16 + nin) * 4096 + kt * 32 + kq * 8;
        fm_chunk(src, w2t + (size_t)c * 8);
    }
}

// ---------------------------------------------------------------- attn ----
// r7-verified v2: no LDS, no barriers. Grid 1024 = (b, kvh, qt of 16 rows).
__global__ __launch_bounds__(256, 4) void MultiAttention_60722247631706_attn(
    float* ws)
{
    const __bf16* qbf  = (const __bf16*)ws;
    const __bf16* kbf  = (const __bf16*)(ws + 2097152);
    const __bf16* vtbf = (const __bf16*)(ws + 2621440);
    __bf16*       obf  = (__bf16*)(ws + 8388608);

    const int sb  = xcd_swz(blockIdx.x, 1024);
    const int qt  = sb & 127;
    const int kvh = (sb >> 7) & 3;
    const int b   = sb >> 9;
    const int q0  = qt * 16;
    const int wb  = q0 - 128;

    const int tid  = threadIdx.x;
    const int w    = tid >> 6;
    const int lane = tid & 63;
    const int l16  = lane & 15;
    const int quad = lane >> 4;
    const int h    = kvh * 4 + w;

    const __bf16* Kb = kbf + (size_t)b * 2048 * 256 + kvh * 64;
    const __bf16* Vb = vtbf + (size_t)(b * 4 + kvh) * 64 * 2048;

    bf16x8 qf[2];
#pragma unroll
    for (int kk = 0; kk < 2; ++kk)
        qf[kk] = *(const bf16x8*)(qbf + (size_t)(b * 2048 + q0 + l16) * 1024
                                  + h * 64 + kk * 32 + quad * 8);

    f32x4 oacc[4];
#pragma unroll
    for (int dn = 0; dn < 4; ++dn) {
        f32x4 z = {0.f, 0.f, 0.f, 0.f};
        oacc[dn] = z;
    }
    float m_run = -1e30f, l_run = 0.f;
    const int kclip = -wb;

    for (int kb = 0; kb < 3; ++kb) {
        f32x4 s[4];
#pragma unroll
        for (int km = 0; km < 4; ++km) {
            f32x4 z = {0.f, 0.f, 0.f, 0.f};
            s[km] = z;
        }
#pragma unroll
        for (int kk = 0; kk < 2; ++kk) {
            bf16x8 kf[4];
#pragma unroll
            for (int km = 0; km < 4; ++km) {
                int row = wb + kb * 64 + km * 16 + l16;
                row = (row >= 0 && row < 2048) ? row : 0;   // masked anyway
                kf[km] = *(const bf16x8*)(Kb + (size_t)row * 256
                                          + kk * 32 + quad * 8);
            }
#pragma unroll
            for (int km = 0; km < 4; ++km)
                s[km] = __builtin_amdgcn_mfma_f32_16x16x32_bf16(
                    kf[km], qf[kk], s[km], 0, 0, 0);
        }

        float mx = -1e30f;
#pragma unroll
        for (int km = 0; km < 4; ++km)
#pragma unroll
            for (int r = 0; r < 4; ++r) {
                const int kl  = kb * 64 + km * 16 + quad * 4 + r;
                const int dlt = kl - l16;
                const bool ok = (dlt >= 1) && (dlt <= 128) && (kl >= kclip);
                const float sv = ok ? s[km][r] : -1e30f;
                s[km][r] = sv;
                mx = fmaxf(mx, sv);
            }
        mx = fmaxf(mx, __shfl_xor(mx, 16));
        mx = fmaxf(mx, __shfl_xor(mx, 32));
        const float mnew = fmaxf(fmaxf(m_run, mx), -1e20f);
        const float corr = expf(m_run - mnew);
        m_run = mnew;
        float rowsum = 0.f;
        unsigned cu[4][2];
#pragma unroll
        for (int km = 0; km < 4; ++km) {
#pragma unroll
            for (int r = 0; r < 4; ++r) {
                const float p = expf(s[km][r] - mnew);
                s[km][r] = p;
                rowsum += p;
            }
            cu[km][0] = pk2(s[km][0], s[km][1]);
            cu[km][1] = pk2(s[km][2], s[km][3]);
        }
        rowsum += __shfl_xor(rowsum, 16);
        rowsum += __shfl_xor(rowsum, 32);
        l_run = l_run * corr + rowsum;

#pragma unroll
        for (int r = 0; r < 4; ++r) {
            const float f = __shfl(corr, (lane & 48) | (quad * 4 + r));
            oacc[0][r] *= f; oacc[1][r] *= f;
            oacc[2][r] *= f; oacc[3][r] *= f;
        }

#pragma unroll
        for (int kk = 0; kk < 2; ++kk) {
            bf16x8 vf[4];
#pragma unroll
            for (int dn = 0; dn < 4; ++dn) {
                int t = wb + kb * 64 + kk * 32 + quad * 8;
                t = (t >= 0 && t <= 2040) ? t : 0;
                vf[dn] = *(const bf16x8*)(Vb + (size_t)(dn * 16 + l16) * 2048 + t);
            }
            const int srcA = ((quad & 1) * 32) + l16;
            const int hi   = quad >> 1;
            const unsigned a0 = (unsigned)__shfl((int)cu[2*kk  ][0], srcA);
            const unsigned a1 = (unsigned)__shfl((int)cu[2*kk  ][1], srcA);
            const unsigned b0 = (unsigned)__shfl((int)cu[2*kk+1][0], srcA);
            const unsigned b1 = (unsigned)__shfl((int)cu[2*kk+1][1], srcA);
            const unsigned c0 = (unsigned)__shfl((int)cu[2*kk  ][0], srcA + 16);
            const unsigned c1 = (unsigned)__shfl((int)cu[2*kk  ][1], srcA + 16);
            const unsigned d0 = (unsigned)__shfl((int)cu[2*kk+1][0], srcA + 16);
            const unsigned d1 = (unsigned)__shfl((int)cu[2*kk+1][1], srcA + 16);
            union { unsigned u[4]; bf16x8 v; } af;
            af.u[0] = hi ? b0 : a0;
            af.u[1] = hi ? b1 : a1;
            af.u[2] = hi ? d0 : c0;
            af.u[3] = hi ? d1 : c1;
#pragma unroll
            for (int dn = 0; dn < 4; ++dn)
                oacc[dn] = __builtin_amdgcn_mfma_f32_16x16x32_bf16(
                    af.v, vf[dn], oacc[dn], 0, 0, 0);
        }
    }

    const float rl = 1.f / l_run;
#pragma unroll
    for (int r = 0; r < 4; ++r) {
        const float f = __shfl(rl, (lane & 48) | (quad * 4 + r));
        const int q = q0 + quad * 4 + r;
        __bf16* op = obf + ((size_t)(b * 2048 + q)) * 1024 + h * 64 + l16;
#pragma unroll
        for (int dn = 0; dn < 4; ++dn)
            op[dn * 16] = (__bf16)(oacc[dn][r] * f);
    }
}

// ------------------------------------------------------------------ p0 ----
// r7-verified: QKV GEMM + fused RoPE -> q/k/vt. 64x128 tile, grid 768.
__global__ __launch_bounds__(256, 4) void MultiAttention_60722247631706_p0(
    float* ws)
{
    __bf16* qbf    = (__bf16*)ws;
    __bf16* kbf    = (__bf16*)(ws + 2097152);
    __bf16* vtbf   = (__bf16*)(ws + 2621440);
    __bf16* xbf    = (__bf16*)(ws + 6291456);
    __bf16* wqkvbf = (__bf16*)(ws + 8388608);

    const int tid = threadIdx.x;

    __bf16* As = (__bf16*)smem;       // [64][64]
    __bf16* Bs = As + 64 * 64;        // [128][64]

    const int bid  = xcd_swz(blockIdx.x, 768);
    const int tm   = bid / 12;
    const int tn   = bid % 12;
    const int w    = tid >> 6;
    const int lane = tid & 63;
    const int wr   = w >> 1;
    const int wc   = w & 1;
    const int l16  = lane & 15;
    const int quad = lane >> 4;
    const int srow = lane >> 3;
    const int sch  = ((lane & 7) ^ srow) * 8;

    const __bf16* ga0 = xbf    + (size_t)(tm * 64  + w * 16 + srow) * 1024 + sch;
    const __bf16* gb0 = wqkvbf + (size_t)(tn * 128 + w * 32 + srow) * 1024 + sch;

    f32x4 zero = {0.f, 0.f, 0.f, 0.f};
    f32x4 acc[2][4];
#pragma unroll
    for (int mi = 0; mi < 2; ++mi)
#pragma unroll
        for (int ni = 0; ni < 4; ++ni) acc[mi][ni] = zero;

    for (int k0 = 0; k0 < 1024; k0 += 64) {
#pragma unroll
        for (int i = 0; i < 2; ++i)
            GLOAD_LDS16(ga0 + (size_t)i * 8 * 1024 + k0, As + (w * 16 + i * 8) * 64);
#pragma unroll
        for (int i = 0; i < 4; ++i)
            GLOAD_LDS16(gb0 + (size_t)i * 8 * 1024 + k0, Bs + (w * 32 + i * 8) * 64);
        __syncthreads();
#pragma unroll
        for (int kk = 0; kk < 2; ++kk) {
            const int cs = ((kk * 4 + quad) ^ (l16 & 7)) * 8;
            bf16x8 af[2], bfr[4];
#pragma unroll
            for (int mi = 0; mi < 2; ++mi)
                af[mi] = *(const bf16x8*)(As + (size_t)(wr * 32 + mi * 16 + l16) * 64 + cs);
#pragma unroll
            for (int ni = 0; ni < 4; ++ni)
                bfr[ni] = *(const bf16x8*)(Bs + (size_t)(wc * 64 + ni * 16 + l16) * 64 + cs);
#pragma unroll
            for (int mi = 0; mi < 2; ++mi)
#pragma unroll
                for (int ni = 0; ni < 4; ++ni)
                    acc[mi][ni] = __builtin_amdgcn_mfma_f32_16x16x32_bf16(
                        af[mi], bfr[ni], acc[mi][ni], 0, 0, 0);
        }
        __syncthreads();
    }

    const int mbase = tm * 64 + wr * 32;
    const int nbase = tn * 128 + wc * 64;

    if (nbase < 1280) {
        const bool isQ = nbase < 1024;
        const float inv1 = powf(10000.f, -(float)l16 / 32.f);
        const float inv2 = powf(10000.f, -(float)(16 + l16) / 32.f);
#pragma unroll
        for (int mi = 0; mi < 2; ++mi) {
#pragma unroll
            for (int r = 0; r < 4; ++r) {
                const int m = mbase + mi * 16 + quad * 4 + r;
                const int t = m & 2047;
                float v0 = acc[mi][0][r], v1 = acc[mi][1][r];
                float v2 = acc[mi][2][r], v3 = acc[mi][3][r];
                const float a1 = (float)t * inv1, a2 = (float)t * inv2;
                const float c1 = cosf(a1), s1 = sinf(a1);
                const float c2 = cosf(a2), s2 = sinf(a2);
                float n0 = v0 * c1 - v2 * s1;
                float n2 = v0 * s1 + v2 * c1;
                float n1 = v1 * c2 - v3 * s2;
                float n3 = v1 * s2 + v3 * c2;
                if (isQ) { n0 *= 0.125f; n1 *= 0.125f; n2 *= 0.125f; n3 *= 0.125f; }
                __bf16* dst = isQ
                    ? qbf + (size_t)m * 1024 + nbase + l16
                    : kbf + (size_t)m * 256 + (nbase - 1024) + l16;
                dst[0]  = (__bf16)n0; dst[16] = (__bf16)n1;
                dst[32] = (__bf16)n2; dst[48] = (__bf16)n3;
            }
        }
    } else {
        const int kvh = (nbase - 1280) >> 6;
        const int bb  = mbase >> 11;
        const int tb  = mbase & 2047;
#pragma unroll
        for (int mi = 0; mi < 2; ++mi) {
#pragma unroll
            for (int ni = 0; ni < 4; ++ni) {
                const int d = ni * 16 + l16;
                bf16x4 pv;
                pv[0] = (__bf16)acc[mi][ni][0]; pv[1] = (__bf16)acc[mi][ni][1];
                pv[2] = (__bf16)acc[mi][ni][2]; pv[3] = (__bf16)acc[mi][ni][3];
                *(bf16x4*)(vtbf + ((size_t)(bb * 4 + kvh) * 64 + d) * 2048
                           + tb + mi * 16 + quad * 4) = pv;
            }
        }
    }
}

// ---------------------------------------------------------------- ffn1 ----
// H = silu(o@W1^T): hybrid — A (o rows) LDS-staged, B (W1) FM-global.
// 128x128 tile, 4 waves, grid 1024 (4/CU). LDS 16 KiB (A only).
__global__ __launch_bounds__(256, 4) void MultiAttention_60722247631706_ffn1(
    float* ws)
{
    __bf16*       obf = (__bf16*)(ws + 8388608);
    const __bf16* w1t = (const __bf16*)(ws + 10485760);
    __bf16*       hbf = (__bf16*)ws;

    const int tid = threadIdx.x;

    __bf16* As = (__bf16*)smem;       // [128][64]

    const int bid  = xcd_swz(blockIdx.x, 1024);
    const int tm   = bid >> 5;
    const int tn   = bid & 31;
    const int w    = tid >> 6;
    const int lane = tid & 63;
    const int wr   = w >> 1;
    const int wc   = w & 1;
    const int l16  = lane & 15;
    const int quad = lane >> 4;
    const int srow = lane >> 3;
    const int sch  = ((lane & 7) ^ srow) * 8;
    const int lo   = l16 * 32 + quad * 8;   // FM lane offset

    const __bf16* ga0 = obf + (size_t)(tm * 128 + w * 32 + srow) * 1024 + sch;
    const __bf16* wb0 = w1t + (size_t)(tn * 8 + wc * 4) * 32 * 512 + lo;

    f32x4 zero = {0.f, 0.f, 0.f, 0.f};
    f32x4 acc[4][4];
#pragma unroll
    for (int mi = 0; mi < 4; ++mi)
#pragma unroll
        for (int ni = 0; ni < 4; ++ni) acc[mi][ni] = zero;

    for (int k0 = 0; k0 < 1024; k0 += 64) {
#pragma unroll
        for (int i = 0; i < 4; ++i)
            GLOAD_LDS16(ga0 + (size_t)i * 8 * 1024 + k0, As + (w * 32 + i * 8) * 64);
        __syncthreads();
#pragma unroll
        for (int kk = 0; kk < 2; ++kk) {
            const int kt = (k0 >> 5) + kk;
            bf16x8 bfr[4];
#pragma unroll
            for (int ni = 0; ni < 4; ++ni)        // B first: overlap L2 latency
                bfr[ni] = *(const bf16x8*)(wb0 + ((size_t)ni * 32 + kt) * 512);
            const int cs = ((kk * 4 + quad) ^ (l16 & 7)) * 8;
            bf16x8 af[4];
#pragma unroll
            for (int mi = 0; mi < 4; ++mi)
                af[mi] = *(const bf16x8*)(As + (size_t)(wr * 64 + mi * 16 + l16) * 64 + cs);
#pragma unroll
            for (int mi = 0; mi < 4; ++mi)
#pragma unroll
                for (int ni = 0; ni < 4; ++ni)
                    acc[mi][ni] = __builtin_amdgcn_mfma_f32_16x16x32_bf16(
                        af[mi], bfr[ni], acc[mi][ni], 0, 0, 0);
        }
        __syncthreads();
    }

#pragma unroll
    for (int mi = 0; mi < 4; ++mi) {
#pragma unroll
        for (int r = 0; r < 4; ++r) {
            const int m = tm * 128 + wr * 64 + mi * 16 + quad * 4 + r;
            __bf16* hp = hbf + (size_t)m * 4096 + tn * 128 + wc * 64 + l16;
#pragma unroll
            for (int ni = 0; ni < 4; ++ni) {
                const float v = acc[mi][ni][r];
                hp[ni * 16] = (__bf16)(v / (1.f + expf(-v)));   // silu
            }
        }
    }
}

// ---------------------------------------------------------------- ffn2 ----
// out += H_ks @ W2_ks^T: hybrid — A (h rows) LDS-staged, B (W2) FM-global.
// 64x128 tile, split-K x2, grid 1024 (4/CU), atomicAdd. LDS 8 KiB.
__global__ __launch_bounds__(256, 4) void MultiAttention_60722247631706_ffn2(
    float* out, float* ws)
{
    const __bf16* hbf = (const __bf16*)ws;
    const __bf16* w2t = (const __bf16*)(ws + 8388608);

    int bid = xcd_swz(blockIdx.x, 1024);
    const int ks = bid >> 9;  bid &= 511;
    const int tm = bid >> 3;          // 0..63
    const int tn = bid & 7;           // 0..7
    const int kbase = ks * 2048;
    const int ktb   = ks * 64;

    const int tid  = threadIdx.x;
    const int w    = tid >> 6;
    const int lane = tid & 63;
    const int wr   = w >> 1;          // 0..1 (M half, 32 rows)
    const int wc   = w & 1;           // 0..1 (N half, 64 cols)
    const int l16  = lane & 15;
    const int quad = lane >> 4;
    const int srow = lane >> 3;
    const int sch  = ((lane & 7) ^ srow) * 8;
    const int lo   = l16 * 32 + quad * 8;

    __bf16* As = (__bf16*)smem;       // [64][64]

    const __bf16* ga0 = hbf + (size_t)(tm * 64 + w * 16 + srow) * 4096 + kbase + sch;
    const __bf16* wb0 = w2t + (size_t)(tn * 8 + wc * 4) * 128 * 512 + lo;

    f32x4 zero = {0.f, 0.f, 0.f, 0.f};
    f32x4 acc[2][4];
#pragma unroll
    for (int mi = 0; mi < 2; ++mi)
#pragma unroll
        for (int ni = 0; ni < 4; ++ni) acc[mi][ni] = zero;

    for (int k0 = 0; k0 < 2048; k0 += 64) {
#pragma unroll
        for (int i = 0; i < 2; ++i)
            GLOAD_LDS16(ga0 + (size_t)i * 8 * 4096 + k0, As + (w * 16 + i * 8) * 64);
        __syncthreads();
#pragma unroll
        for (int kk = 0; kk < 2; ++kk) {
            const int kt = ktb + (k0 >> 5) + kk;
            bf16x8 bfr[4];
#pragma unroll
            for (int ni = 0; ni < 4; ++ni)
                bfr[ni] = *(const bf16x8*)(wb0 + ((size_t)ni * 128 + kt) * 512);
            const int cs = ((kk * 4 + quad) ^ (l16 & 7)) * 8;
            bf16x8 af[2];
#pragma unroll
            for (int mi = 0; mi < 2; ++mi)
                af[mi] = *(const bf16x8*)(As + (size_t)(wr * 32 + mi * 16 + l16) * 64 + cs);
#pragma unroll
            for (int mi = 0; mi < 2; ++mi)
#pragma unroll
                for (int ni = 0; ni < 4; ++ni)
                    acc[mi][ni] = __builtin_amdgcn_mfma_f32_16x16x32_bf16(
                        af[mi], bfr[ni], acc[mi][ni], 0, 0, 0);
        }
        __syncthreads();
    }

#pragma unroll
    for (int mi = 0; mi < 2; ++mi) {
#pragma unroll
        for (int r = 0; r < 4; ++r) {
            const int m = tm * 64 + wr * 32 + mi * 16 + quad * 4 + r;
            float* op = out + (size_t)m * 1024 + tn * 128 + wc * 64 + l16;
#pragma unroll
            for (int ni = 0; ni < 4; ++ni)
                atomicAdd(op + ni * 16, acc[mi][ni][r]);
        }
    }
}

extern "C" void kernel_launch(void* const* d_in, const int* in_sizes, int n_in,
                              void* d_out, int out_size, void* d_ws, size_t ws_size,
                              hipStream_t stream)
{
    const float* x  = (const float*)d_in[0];
    const float* Wq = (const float*)d_in[1];
    const float* Wk = (const float*)d_in[2];
    const float* Wv = (const float*)d_in[3];
    const float* W1 = (const float*)d_in[4];
    const float* W2 = (const float*)d_in[5];
    float* out = (float*)d_out;
    float* ws  = (float*)d_ws;

    const int P0_LDS   = (64 + 128) * 64 * 2;   // 24576 B
    const int FFN1_LDS = 128 * 64 * 2;          // 16384 B (A only)
    const int FFN2_LDS = 64 * 64 * 2;           // 8192 B  (A only)

    // conv5: x/wqkv row bf16, W1 -> FM, zero out
    MultiAttention_60722247631706_conv5<<<2048, 256, 0, stream>>>(
        x, Wq, Wk, Wv, W1, out, ws);
    // p0: QKV GEMM + fused RoPE -> q_bf / k_bf / vt_bf
    MultiAttention_60722247631706_p0<<<768, 256, P0_LDS, stream>>>(ws);
    // attention v2 -> o_bf (row-major)
    MultiAttention_60722247631706_attn<<<1024, 256, 0, stream>>>(ws);
    // ffn1 (hybrid) -> h_bf
    MultiAttention_60722247631706_ffn1<<<1024, 256, FFN1_LDS, stream>>>(ws);
    // conv6: W2 -> FM (over dead o_bf)
    MultiAttention_60722247631706_conv6<<<1024, 256, 0, stream>>>(W2, ws);
    // ffn2 (hybrid): split-K x2, atomicAdd into out
    MultiAttention_60722247631706_ffn2<<<1024, 256, FFN2_LDS, stream>>>(out, ws);
}